// Round 16
// baseline (236.642 us; speedup 1.0000x reference)
//
#include <hip/hip_runtime.h>
#include <hip/hip_bf16.h>
#include <stdint.h>
#include <limits.h>

#define BB 8192
#define DIM 256   // elements per row; i8 row = 256 bytes

typedef __attribute__((ext_vector_type(4))) int int32x4;

// async global->LDS, 16B per lane. LDS dest must be wave-uniform base + lane*16.
__device__ __forceinline__ void load_lds16(const char* g, char* l) {
  __builtin_amdgcn_global_load_lds(
      (const __attribute__((address_space(1))) unsigned int*)g,
      (__attribute__((address_space(3))) unsigned int*)l, 16, 0, 0);
}

// quantize normalized element to i8 with scale 256 (data max |x| ~ 0.31, no clip)
__device__ __forceinline__ float q8f(float x) {
  return rintf(fmaxf(fminf(x * 256.f, 127.f), -127.f));
}

__device__ __forceinline__ int imax(int a, int b) { return a > b ? a : b; }

// 16-lane max-reduce on the VALU pipe via DPP (R10-validated: keeps DS free).
__device__ __forceinline__ int dpp_max16(int u) {
  int t;
  t = __builtin_amdgcn_update_dpp(0, u, 0xB1, 0xF, 0xF, true);   // quad_perm [1,0,3,2]
  u = t > u ? t : u;
  t = __builtin_amdgcn_update_dpp(0, u, 0x4E, 0xF, 0xF, true);   // quad_perm [2,3,0,1]
  u = t > u ? t : u;
  t = __builtin_amdgcn_update_dpp(0, u, 0x124, 0xF, 0xF, true);  // row_ror:4
  u = t > u ? t : u;
  t = __builtin_amdgcn_update_dpp(0, u, 0x128, 0xF, 0xF, true);  // row_ror:8
  u = t > u ? t : u;
  return u;
}

// ---------------------------------------------------------------------------
// Phase 1: one wave per row. A matrices written FRAGMENT-MAJOR (R14):
// element (row,k) at tileR*4096 + kchunk*256 + (row&15)*16 + (k&15), so a
// GEMM wave's A-operand load is base + lane*16 (coalesced dwordx4, no LDS).
// gt stays row-major (B DMA path). Also: per-row cos, exact integer
// diagonals, maxComb/sums/ticket init.
// ---------------------------------------------------------------------------
__global__ __launch_bounds__(256) void phase1(
    const float* __restrict__ vp,  const float* __restrict__ tp,
    const float* __restrict__ vfp, const float* __restrict__ ce,
    const float* __restrict__ nr,
    float* __restrict__ rowcos, int* __restrict__ diag,
    char* __restrict__ abuf,   // [3][BB*DIM] fragment-major: z=0 gt_v,1 v,2 narr
    char* __restrict__ gtbuf,  // row-major
    int* __restrict__ maxComb, float* __restrict__ sums,
    int* __restrict__ ticket) {
  __shared__ unsigned ldsT[3][4][64];
  const int wave = threadIdx.x >> 6;
  const int lane = threadIdx.x & 63;
  const int row  = blockIdx.x * 4 + wave;
  const int base = row * DIM + lane * 4;

  float4 a = *(const float4*)&vp[base];
  float4 t = *(const float4*)&tp[base];
  float4 g = *(const float4*)&vfp[base];
  float4 c = *(const float4*)&ce[base];
  float4 n = *(const float4*)&nr[base];

  float s[7];
  s[0] = a.x*a.x + a.y*a.y + a.z*a.z + a.w*a.w;  // |vp|^2
  s[1] = g.x*g.x + g.y*g.y + g.z*g.z + g.w*g.w;  // |vfp|^2
  s[2] = a.x*g.x + a.y*g.y + a.z*g.z + a.w*g.w;  // vp.vfp
  s[3] = t.x*t.x + t.y*t.y + t.z*t.z + t.w*t.w;  // |tp|^2
  s[4] = c.x*c.x + c.y*c.y + c.z*c.z + c.w*c.w;  // |ce|^2
  s[5] = t.x*c.x + t.y*c.y + t.z*c.z + t.w*c.w;  // tp.ce
  s[6] = n.x*n.x + n.y*n.y + n.z*n.z + n.w*n.w;  // |narr|^2

  #pragma unroll
  for (int mk = 1; mk < 64; mk <<= 1) {
    #pragma unroll
    for (int q = 0; q < 7; ++q) s[q] += __shfl_xor(s[q], mk);
  }

  const float eps = 1e-8f;
  float na = fmaxf(sqrtf(s[0]), eps);
  float ng = fmaxf(sqrtf(s[1]), eps);
  float nt = fmaxf(sqrtf(s[3]), eps);
  float nc = fmaxf(sqrtf(s[4]), eps);
  float nn = fmaxf(sqrtf(s[6]), eps);
  float ia = 1.f / na, ig = 1.f / ng, ic = 1.f / nc, in_ = 1.f / nn;

  float qa0=q8f(a.x*ia), qa1=q8f(a.y*ia), qa2=q8f(a.z*ia), qa3=q8f(a.w*ia);
  float qg0=q8f(g.x*ig), qg1=q8f(g.y*ig), qg2=q8f(g.z*ig), qg3=q8f(g.w*ig);
  float qn0=q8f(n.x*in_),qn1=q8f(n.y*in_),qn2=q8f(n.z*in_),qn3=q8f(n.w*in_);
  float qc0=q8f(c.x*ic), qc1=q8f(c.y*ic), qc2=q8f(c.z*ic), qc3=q8f(c.w*ic);

  // exact integer diagonal sims (fp32-exact: |prod|<=127^2, sums < 2^24)
  float d[3];
  d[0] = qg0*qc0 + qg1*qc1 + qg2*qc2 + qg3*qc3;
  d[1] = qa0*qc0 + qa1*qc1 + qa2*qc2 + qa3*qc3;
  d[2] = qn0*qc0 + qn1*qc1 + qn2*qc2 + qn3*qc3;
  #pragma unroll
  for (int mk = 1; mk < 64; mk <<= 1) {
    #pragma unroll
    for (int q = 0; q < 3; ++q) d[q] += __shfl_xor(d[q], mk);
  }

  auto pack = [](float x0, float x1, float x2, float x3) -> unsigned {
    return ((unsigned)((int)x0 & 0xFF)) | ((unsigned)((int)x1 & 0xFF) << 8) |
           ((unsigned)((int)x2 & 0xFF) << 16) | ((unsigned)((int)x3 & 0xFF) << 24);
  };
  // gt: row-major (the GEMM B-DMA consumes this)
  ((unsigned*)gtbuf)[row * 64 + lane] = pack(qc0, qc1, qc2, qc3);
  // A matrices: stage packed rows in LDS for the fragment-major transpose
  ldsT[0][wave][lane] = pack(qg0, qg1, qg2, qg3);
  ldsT[1][wave][lane] = pack(qa0, qa1, qa2, qa3);
  ldsT[2][wave][lane] = pack(qn0, qn1, qn2, qn3);

  if (lane == 0) {
    rowcos[row]        = s[2] / (na * ng);   // vis cos (fp32, for the loss)
    rowcos[BB + row]   = s[5] / (nt * nc);   // text cos
    diag[0 * BB + row] = (int)d[0];
    diag[1 * BB + row] = (int)d[1];
    diag[2 * BB + row] = (int)d[2];
    maxComb[0 * BB + row] = INT_MIN;         // accumulator init (replaces memset)
    maxComb[1 * BB + row] = INT_MIN;
    maxComb[2 * BB + row] = INT_MIN;
  }
  if (blockIdx.x == 0 && threadIdx.x < 5) sums[threadIdx.x] = 0.f;
  if (blockIdx.x == 0 && threadIdx.x == 5) *ticket = 0;

  __syncthreads();
  // transpose-store: thread t -> matrix t>>6, lane l=t&63 stores 16 B of
  // row (blk&3)*4 + (l&3), k-chunk l>>2. Contiguous 64B segments.
  if (threadIdx.x < 192) {
    int mat = threadIdx.x >> 6, l = threadIdx.x & 63;
    int kc = l >> 2, j = l & 3;
    uint4 val = *(const uint4*)&ldsT[mat][j][kc * 4];
    int tileR = blockIdx.x >> 2;
    int rm    = (blockIdx.x & 3) * 4 + j;
    *(uint4*)&abuf[(size_t)mat * BB * DIM + tileR * 4096 + kc * 256 + rm * 16] = val;
  }
}

// ---------------------------------------------------------------------------
// Phase 2 (R16): MERGED-Z SEQUENTIAL. One 4-wave block computes the 128x128
// tile of ALL THREE sim matrices: the B panel (shared by all z -- the 't'
// side is always gt_t) is staged ONCE (full-K 32 KB, one DMA drain), then
// z=0,1,2 run back-to-back reusing the same 16 acc VGPRs. vs R15:
//   - blocks 12288 -> 4096: every per-block fixed cost (B-DMA drain ~2000cyc,
//     startup, barrier) amortized 3x;
//   - B DMA traffic /3 (L2 load was ~18 TB/s, half the ceiling);
//   - cross-z A prefetch hides the z-boundary under the prior epilogue.
// R4's merged-z failed with CONCURRENT z (12 waves, 70 KB, 1 block/CU);
// sequential keeps 4 waves + 35 KB -> 4 blocks/CU.
// A streamed fragment-major (R14), XOR swizzle p=c^(row&15) (0 conflicts),
// split diagonal/off-diagonal epilogue (R15), DPP reduce (R10).
// Integer sims are EXACT: w = 2*sim + (j<i) vs 2*diag reproduces argmax
// first-index tie semantics exactly.
// ---------------------------------------------------------------------------
__global__ __launch_bounds__(256, 4) void sim_argmax(
    const char* __restrict__ Af, const char* __restrict__ B,
    int* __restrict__ maxComb) {
  __shared__ char Bs[128 * 256];
  __shared__ int comb[3][128][2];

  const int tid  = threadIdx.x;
  const int lane = tid & 63;
  const int wave = tid >> 6;
  const int wr   = wave >> 1, wc = wave & 1;
  const int m    = lane & 15, quad = lane >> 4;

  const int rowTile = blockIdx.y * 128;
  const int colTile = blockIdx.x * 128;
  const char* A0 = Af + (size_t)(rowTile >> 4) * 4096;   // + z*BB*DIM
  const char* Bp = B + (size_t)colTile * DIM;

  // stage the full-K B panel ONCE: 2048 16B chunks, 8/thread, XOR-swizzled
  #pragma unroll
  for (int t = 0; t < 8; ++t) {
    const int c   = t * 256 + tid;
    const int row = c >> 4;
    const int l   = (c & 15) ^ (row & 15);
    load_lds16(&Bp[row * DIM + l * 16], &Bs[c * 16]);
  }

  // prefetch z=0, kp=0 A fragments (hidden under the B-DMA drain)
  int32x4 af[4];
  #pragma unroll
  for (int rt = 0; rt < 4; ++rt)
    af[rt] = *(const int32x4*)&A0[(size_t)(wr * 4 + rt) * 4096 + lane * 16];

  __syncthreads();   // the ONLY staging barrier of the whole block

  const bool offDiag = (blockIdx.x != blockIdx.y);
  const int  addOne  = (blockIdx.y > blockIdx.x) ? 1 : 0;
  const int rowBase = rowTile + wr * 64;
  const int colBase = colTile + wc * 64;

  #pragma unroll
  for (int z = 0; z < 3; ++z) {
    int32x4 acc[4][4];
    #pragma unroll
    for (int i = 0; i < 4; ++i)
      #pragma unroll
      for (int j = 0; j < 4; ++j) acc[i][j] = (int32x4){0, 0, 0, 0};

    #pragma unroll
    for (int kp = 0; kp < 4; ++kp) {
      int32x4 a[4];
      #pragma unroll
      for (int rt = 0; rt < 4; ++rt) a[rt] = af[rt];
      // prefetch next fragment set (next kp, or next z's kp=0)
      int nz = z, nkp = kp + 1;
      if (nkp == 4) { nz = z + 1; nkp = 0; }
      if (nz < 3) {
        const char* An = A0 + (size_t)nz * BB * DIM;
        #pragma unroll
        for (int rt = 0; rt < 4; ++rt)
          af[rt] = *(const int32x4*)&An[(size_t)(wr * 4 + rt) * 4096 +
                                        nkp * 1024 + lane * 16];
      }
      int32x4 bf[4];
      #pragma unroll
      for (int ct = 0; ct < 4; ++ct) {
        int br = wc * 64 + ct * 16 + m;
        int p  = (kp * 4 + quad) ^ m;        // swizzle inverse; 2-way = free
        bf[ct] = *(const int32x4*)&Bs[br * 256 + p * 16];
      }
      #pragma unroll
      for (int rt = 0; rt < 4; ++rt)
        #pragma unroll
        for (int ct = 0; ct < 4; ++ct)
          acc[rt][ct] = __builtin_amdgcn_mfma_i32_16x16x64_i8(
              a[rt], bf[ct], acc[rt][ct], 0, 0, 0);
    }

    // Epilogue for this z: C/D layout col=lane&15, row=quad*4+reg.
    if (offDiag) {
      // j<i tile-uniform: reduce raw sims, transform once per row (R15).
      #pragma unroll
      for (int rt = 0; rt < 4; ++rt) {
        #pragma unroll
        for (int reg = 0; reg < 4; ++reg) {
          int u = imax(imax(acc[rt][0][reg], acc[rt][1][reg]),
                       imax(acc[rt][2][reg], acc[rt][3][reg]));
          u = dpp_max16(u);
          if (m == 0)
            comb[z][wr * 64 + rt * 16 + quad * 4 + reg][wc] = u * 2 + addOne;
        }
      }
    } else {
      // diagonal block: exact per-element w = 2*sim + (j<i), skip j==i.
      #pragma unroll
      for (int rt = 0; rt < 4; ++rt) {
        #pragma unroll
        for (int reg = 0; reg < 4; ++reg) {
          int i = rowBase + rt * 16 + quad * 4 + reg;
          int u = INT_MIN;
          #pragma unroll
          for (int ct = 0; ct < 4; ++ct) {
            int j = colBase + ct * 16 + m;
            int w = acc[rt][ct][reg] * 2 + ((j < i) ? 1 : 0);
            w = (j == i) ? INT_MIN : w;
            u = imax(u, w);
          }
          u = dpp_max16(u);
          if (m == 0) comb[z][wr * 64 + rt * 16 + quad * 4 + reg][wc] = u;
        }
      }
    }
  }

  __syncthreads();   // all comb[z] writes resident
  if (tid < 128) {
    #pragma unroll
    for (int z = 0; z < 3; ++z) {
      int u = imax(comb[z][tid][0], comb[z][tid][1]);
      atomicMax(&maxComb[(size_t)z * BB + rowTile + tid], u);
    }
  }
}

// ---------------------------------------------------------------------------
// Phase 3 (+fused finalize, R9-validated): 32 blocks; per-row verdicts + loss
// sums block-reduced -> 5 atomics/block; last block (ticket) writes 9 outputs.
// argmax==i  <=>  2*diag >= maxComb  (exact integer semantics)
// ---------------------------------------------------------------------------
__global__ __launch_bounds__(256) void phase3_fin(
    const int* __restrict__ diag, const int* __restrict__ maxComb,
    const float* __restrict__ rowcos,
    float* __restrict__ sums, int* __restrict__ ticket,
    float* __restrict__ out) {
  __shared__ float red[4][5];
  __shared__ bool amLast;
  int r = blockIdx.x * 256 + threadIdx.x;
  int lane = threadIdx.x & 63, wave = threadIdx.x >> 6;
  float v[5];
  v[0] = rowcos[r];
  v[1] = rowcos[BB + r];
  #pragma unroll
  for (int z = 0; z < 3; ++z)
    v[2 + z] = (2 * diag[z * BB + r] >= maxComb[z * BB + r]) ? 1.f : 0.f;
  #pragma unroll
  for (int mk = 1; mk < 64; mk <<= 1) {
    #pragma unroll
    for (int q = 0; q < 5; ++q) v[q] += __shfl_xor(v[q], mk);
  }
  if (lane == 0) {
    #pragma unroll
    for (int q = 0; q < 5; ++q) red[wave][q] = v[q];
  }
  __syncthreads();
  if (threadIdx.x < 5) {
    float acc = red[0][threadIdx.x] + red[1][threadIdx.x] +
                red[2][threadIdx.x] + red[3][threadIdx.x];
    atomicAdd(&sums[threadIdx.x], acc);
  }
  __threadfence();
  __syncthreads();
  if (threadIdx.x == 0)
    amLast = (atomicAdd(ticket, 1) == (int)gridDim.x - 1);
  __syncthreads();
  if (amLast && threadIdx.x == 0) {
    float s0 = atomicAdd(&sums[0], 0.f);
    float s1 = atomicAdd(&sums[1], 0.f);
    float s2 = atomicAdd(&sums[2], 0.f);
    float s3 = atomicAdd(&sums[3], 0.f);
    float s4 = atomicAdd(&sums[4], 0.f);
    float vl = 1.f - s0 * (1.f / BB);
    float tl = 1.f - s1 * (1.f / BB);
    out[0] = vl;
    out[1] = tl;
    out[2] = vl + tl;
    float a0 = s2 * (100.f / BB);
    float a1 = s3 * (100.f / BB);
    float a2 = s4 * (100.f / BB);
    out[3] = a0;  // gt_v - gt_t
    out[4] = a1;  // v    - gt_t
    out[5] = a0;  // gt_v - t   (t side is gt_t in the original code)
    out[6] = a1;  // v    - t
    out[7] = a2;  // narr - gt_t
    out[8] = a2;  // narr - t
  }
}

extern "C" void kernel_launch(void* const* d_in, const int* in_sizes, int n_in,
                              void* d_out, int out_size, void* d_ws, size_t ws_size,
                              hipStream_t stream) {
  const float* vp  = (const float*)d_in[0];
  const float* tp  = (const float*)d_in[1];
  const float* vfp = (const float*)d_in[2];
  const float* ce  = (const float*)d_in[3];
  const float* nr  = (const float*)d_in[4];

  char* ws = (char*)d_ws;
  float* sums    = (float*)ws;                      // 5 floats
  int*   ticket  = (int*)(ws + 32);                 // phase3 ticket
  int*   maxComb = (int*)(ws + 64);                 // 3*BB ints
  int*   diag    = maxComb + 3 * BB;                // 3*BB ints
  float* rowcos  = (float*)(diag + 3 * BB);         // 2*BB floats
  char*  abuf    = (char*)(rowcos + 2 * BB);        // 3*BB*DIM fragment-major A
  char*  gtbuf   = abuf + (size_t)3 * BB * DIM;     // BB*DIM row-major gt

  // no memsets: phase1 initializes maxComb, sums, ticket

  phase1<<<BB / 4, 256, 0, stream>>>(vp, tp, vfp, ce, nr, rowcos, diag,
                                     abuf, gtbuf, maxComb, sums, ticket);

  dim3 grid(BB / 128, BB / 128);
  sim_argmax<<<grid, 256, 0, stream>>>(abuf, gtbuf, maxComb);

  phase3_fin<<<BB / 256, 256, 0, stream>>>(diag, maxComb, rowcos, sums, ticket,
                                           (float*)d_out);
}